// Round 8
// baseline (176.427 us; speedup 1.0000x reference)
//
#include <hip/hip_runtime.h>
#include <math.h>

#define DIMS 32
#define NROWS 4096
#define MROWS 8192
#define HID 100

#define L2E 1.44269504088896340736f

// bf16 LDS row stride: 40 bf16 = 80 B = 5 bank-quads -> ds_read/write_b128 at
// conflict-free floor (quad-col = (5*row + q) & 7 covers all 8 per 8 rows).
#define LROW 40

typedef float f32x4 __attribute__((ext_vector_type(4)));
typedef short bf16x8 __attribute__((ext_vector_type(8)));

__device__ __forceinline__ void load_var(const float* part, float& iv, float& var) {
    float S = 0.0f, Q = 0.0f;
    #pragma unroll
    for (int i = 0; i < 8; i++) { S += part[2 * i]; Q += part[2 * i + 1]; }
    const float cnt = (float)(NROWS * DIMS);
    var = (Q - S * S / cnt) / (cnt - 1.0f);
    iv = 1.0f / var;
}

__device__ __forceinline__ float tanh_fast(float x) {
    float xc = fminf(fmaxf(x, -10.0f), 10.0f);
    float e = __builtin_amdgcn_exp2f(xc * (2.0f * L2E));  // e^(2x)
    return (e - 1.0f) * __builtin_amdgcn_rcpf(e + 1.0f);
}

// float -> bf16 with round-to-nearest-even
__device__ __forceinline__ unsigned short f2bf(float f) {
    unsigned int u = __float_as_uint(f);
    u += 0x7FFFu + ((u >> 16) & 1u);
    return (unsigned short)(u >> 16);
}

// ---------------- Kernel 1: variance partials + collapsed M = W2 @ W1 ----------
// 8 blocks x 256. Block b: partial sum/sumsq of cent chunk b -> part[2b], part[2b+1].
// Block 0 additionally computes Mmat[d][k] = sum_j W2[d*100+j] * W1[j*32+k].
__global__ __launch_bounds__(256) void k_var(const float* __restrict__ c,
                                             const float* __restrict__ W1,
                                             const float* __restrict__ W2,
                                             float* __restrict__ part,
                                             float* __restrict__ Mmat) {
    int b = blockIdx.x, t = threadIdx.x;
    const float4* c4 = (const float4*)c;
    float s = 0.0f, q = 0.0f;
    #pragma unroll
    for (int i = 0; i < 16; i++) {
        float4 a = c4[b * 4096 + i * 256 + t];
        s += a.x + a.y + a.z + a.w;
        q += a.x * a.x + a.y * a.y + a.z * a.z + a.w * a.w;
    }
    #pragma unroll
    for (int off = 32; off > 0; off >>= 1) {
        s += __shfl_down(s, off);
        q += __shfl_down(q, off);
    }
    __shared__ float red[8];
    int lane = t & 63, wid = t >> 6;
    if (lane == 0) { red[wid] = s; red[4 + wid] = q; }
    __syncthreads();
    if (t == 0) {
        part[2 * b]     = red[0] + red[1] + red[2] + red[3];
        part[2 * b + 1] = red[4] + red[5] + red[6] + red[7];
    }
    if (b == 0) {
        __shared__ float w1s[HID * DIMS];
        __shared__ float w2s[DIMS * HID];
        for (int i = t; i < HID * DIMS; i += 256) { w1s[i] = W1[i]; w2s[i] = W2[i]; }
        __syncthreads();
        #pragma unroll
        for (int o = 0; o < 4; o++) {
            int id = o * 256 + t;
            int r = id >> 5, cc = id & 31;
            float a = 0.0f;
            for (int j = 0; j < HID; j++) a += w2s[r * HID + j] * w1s[j * DIMS + cc];
            Mmat[id] = a;
        }
    }
}

// ---------------- Kernel 2 (fused): per-block staging + MFMA + exp2 + store ------
// Each of 2048 blocks owns a 128x128 output tile and is self-sufficient:
//   stage: threads 0..127 read cent strip row -> loc via tanh(cent@M+b2)*cent,
//          pack bf16 to LDS ls; threads 128..255 read x strip row -> pack xs;
//          row norms -> As (hv*xsq+C0) / Bs (hv*lsq) in LDS.
//   compute: per-wave 4x4 fragments of mfma_f32_16x16x32_bf16 (K=32 in one op),
//   epilogue: exp2 + temporal scattered f32x4 stores (R4 pattern, proven best).
// Only cross-block dependency: part/Mmat from k_var.
__global__ __launch_bounds__(256) void k_fused(const float* __restrict__ cent,
                                               const float* __restrict__ x,
                                               const float* __restrict__ b2,
                                               const float* __restrict__ part,
                                               const float* __restrict__ Mmat,
                                               float* __restrict__ out) {
    __shared__ __align__(16) float ms[DIMS * DIMS];
    __shared__ float b2s[DIMS];
    __shared__ __align__(16) unsigned short ls[128 * LROW];  // loc bf16, swizzled quads
    __shared__ __align__(16) unsigned short xs[128 * LROW];  // x   bf16, swizzled quads
    __shared__ float As[128];
    __shared__ float Bs[128];

    float iv, var;
    load_var(part, iv, var);
    const float s  = L2E * iv;
    const float hv = -0.5f * L2E * iv;
    const float C0 = -16.0f * log2f(2.0f * (float)M_PI * var);

    int t = threadIdx.x;
    int lane = t & 63, wid = t >> 6;
    int bid = blockIdx.x;
    int tile = ((bid & 7) << 8) | (bid >> 3);  // 2048 = 8*256: bijective
    int mt = tile >> 5, ntl = tile & 31;
    int mb = mt * 128, nb = ntl * 128;

    #pragma unroll
    for (int i = 0; i < 4; i++) ms[i * 256 + t] = Mmat[i * 256 + t];
    if (t < DIMS) b2s[t] = b2[t];
    __syncthreads();

    // ---- Staging phase ----
    if (t < 128) {
        int row = t;  // n-local
        float c[DIMS];
        const float4* cr = (const float4*)(cent + (size_t)(nb + row) * DIMS);
        #pragma unroll
        for (int i = 0; i < 8; i++) {
            float4 v = cr[i];
            c[4 * i] = v.x; c[4 * i + 1] = v.y; c[4 * i + 2] = v.z; c[4 * i + 3] = v.w;
        }
        float lr[DIMS];
        float lsq = 0.0f;
        #pragma unroll
        for (int d = 0; d < DIMS; d++) {
            const float4* mr = (const float4*)&ms[d * DIMS];
            float a0 = 0.f, a1 = 0.f, a2 = 0.f, a3 = 0.f;
            #pragma unroll
            for (int kk = 0; kk < 8; kk++) {
                float4 m = mr[kk];
                a0 += c[4 * kk] * m.x;
                a1 += c[4 * kk + 1] * m.y;
                a2 += c[4 * kk + 2] * m.z;
                a3 += c[4 * kk + 3] * m.w;
            }
            float v = tanh_fast((a0 + a1) + (a2 + a3) + b2s[d]) * c[d];
            lr[d] = v;
            lsq += v * v;
        }
        uint4* lq = (uint4*)&ls[row * LROW];
        #pragma unroll
        for (int q = 0; q < 4; q++) {
            uint4 w;
            w.x = (unsigned int)f2bf(lr[8 * q + 0]) | ((unsigned int)f2bf(lr[8 * q + 1]) << 16);
            w.y = (unsigned int)f2bf(lr[8 * q + 2]) | ((unsigned int)f2bf(lr[8 * q + 3]) << 16);
            w.z = (unsigned int)f2bf(lr[8 * q + 4]) | ((unsigned int)f2bf(lr[8 * q + 5]) << 16);
            w.w = (unsigned int)f2bf(lr[8 * q + 6]) | ((unsigned int)f2bf(lr[8 * q + 7]) << 16);
            lq[q] = w;
        }
        Bs[row] = hv * lsq;
    } else {
        int row = t - 128;  // m-local
        const float4* xr = (const float4*)(x + (size_t)(mb + row) * DIMS);
        float xv[DIMS];
        float xsq = 0.0f;
        #pragma unroll
        for (int i = 0; i < 8; i++) {
            float4 v = xr[i];
            xv[4 * i] = v.x; xv[4 * i + 1] = v.y; xv[4 * i + 2] = v.z; xv[4 * i + 3] = v.w;
            xsq += v.x * v.x + v.y * v.y + v.z * v.z + v.w * v.w;
        }
        uint4* xq = (uint4*)&xs[row * LROW];
        #pragma unroll
        for (int q = 0; q < 4; q++) {
            uint4 w;
            w.x = (unsigned int)f2bf(xv[8 * q + 0]) | ((unsigned int)f2bf(xv[8 * q + 1]) << 16);
            w.y = (unsigned int)f2bf(xv[8 * q + 2]) | ((unsigned int)f2bf(xv[8 * q + 3]) << 16);
            w.z = (unsigned int)f2bf(xv[8 * q + 4]) | ((unsigned int)f2bf(xv[8 * q + 5]) << 16);
            w.w = (unsigned int)f2bf(xv[8 * q + 6]) | ((unsigned int)f2bf(xv[8 * q + 7]) << 16);
            xq[q] = w;
        }
        As[row] = fmaf(hv, xsq, C0);
    }
    __syncthreads();

    // ---- Fragments from LDS ----
    int ml = (wid >> 1) * 64;  // m-local base of this wave
    int nl = (wid & 1) * 64;   // n-local base
    int r = lane & 15, g = lane >> 4;

    bf16x8 lf[4], xf[4];
    #pragma unroll
    for (int j = 0; j < 4; j++)
        lf[j] = *(const bf16x8*)&ls[(nl + 16 * j + r) * LROW + 8 * g];
    #pragma unroll
    for (int i = 0; i < 4; i++)
        xf[i] = *(const bf16x8*)&xs[(ml + 16 * i + r) * LROW + 8 * g];

    f32x4 zero = {0.0f, 0.0f, 0.0f, 0.0f};
    f32x4 acc[4][4];
    #pragma unroll
    for (int j = 0; j < 4; j++)
        #pragma unroll
        for (int i = 0; i < 4; i++)
            acc[j][i] = __builtin_amdgcn_mfma_f32_16x16x32_bf16(lf[j], xf[i], zero, 0, 0, 0);

    // D layout: col = lane&15 -> m = ml+16i+r;  row = 4*(lane>>4)+reg -> n = nl+16j+4g+q
    float em[4];
    #pragma unroll
    for (int i = 0; i < 4; i++) em[i] = As[ml + 16 * i + r];
    f32x4 en[4];
    #pragma unroll
    for (int j = 0; j < 4; j++) {
        float4 bv = *(const float4*)&Bs[nl + 16 * j + 4 * g];
        en[j].x = bv.x; en[j].y = bv.y; en[j].z = bv.z; en[j].w = bv.w;
    }

    #pragma unroll
    for (int i = 0; i < 4; i++) {
        float* orow = out + (size_t)(mb + ml + 16 * i + r) * NROWS + nb + nl;
        float e = em[i];
        #pragma unroll
        for (int j = 0; j < 4; j++) {
            f32x4 v;
            v.x = __builtin_amdgcn_exp2f(fmaf(s, acc[j][i][0], e + en[j].x));
            v.y = __builtin_amdgcn_exp2f(fmaf(s, acc[j][i][1], e + en[j].y));
            v.z = __builtin_amdgcn_exp2f(fmaf(s, acc[j][i][2], e + en[j].z));
            v.w = __builtin_amdgcn_exp2f(fmaf(s, acc[j][i][3], e + en[j].w));
            *(f32x4*)(orow + 16 * j + 4 * g) = v;
        }
    }
}

extern "C" void kernel_launch(void* const* d_in, const int* in_sizes, int n_in,
                              void* d_out, int out_size, void* d_ws, size_t ws_size,
                              hipStream_t stream) {
    const float* cent = (const float*)d_in[0];
    const float* x    = (const float*)d_in[1];
    const float* W1   = (const float*)d_in[2];
    const float* W2   = (const float*)d_in[3];
    const float* b2   = (const float*)d_in[4];
    float* out = (float*)d_out;

    float* ws   = (float*)d_ws;
    float* part = ws;          // 16 floats
    float* Mmat = ws + 64;     // 1024 floats

    k_var<<<8, 256, 0, stream>>>(cent, W1, W2, part, Mmat);
    k_fused<<<NROWS / 128 * (MROWS / 128), 256, 0, stream>>>(cent, x, b2, part, Mmat, out);
}

// Round 9
// 159.190 us; speedup vs baseline: 1.1083x; 1.1083x over previous
//
#include <hip/hip_runtime.h>
#include <math.h>

#define DIMS 32
#define NROWS 4096
#define MROWS 8192
#define HID 100

#define L2E 1.44269504088896340736f

typedef float f32x4 __attribute__((ext_vector_type(4)));
typedef short bf16x8 __attribute__((ext_vector_type(8)));

__device__ __forceinline__ void load_var(const float* part, float& iv, float& var) {
    float S = 0.0f, Q = 0.0f;
    #pragma unroll
    for (int i = 0; i < 8; i++) { S += part[2 * i]; Q += part[2 * i + 1]; }
    const float cnt = (float)(NROWS * DIMS);
    var = (Q - S * S / cnt) / (cnt - 1.0f);
    iv = 1.0f / var;
}

__device__ __forceinline__ float tanh_fast(float x) {
    float xc = fminf(fmaxf(x, -10.0f), 10.0f);
    float e = __builtin_amdgcn_exp2f(xc * (2.0f * L2E));  // e^(2x)
    return (e - 1.0f) * __builtin_amdgcn_rcpf(e + 1.0f);
}

// float -> bf16 with round-to-nearest-even
__device__ __forceinline__ unsigned short f2bf(float f) {
    unsigned int u = __float_as_uint(f);
    u += 0x7FFFu + ((u >> 16) & 1u);
    return (unsigned short)(u >> 16);
}

// ---------------- Kernel 1 (fused prep): 56 blocks x 256 ----------------
// blocks 0..7   : partial sum/sumsq of centroids -> part   (for var, used by k_pair)
// blocks 8..23  : loc rows via collapsed M=W2@W1 (recomputed per block in LDS)
//                 -> locb (bf16), B[n] = raw ||loc_n||^2
// blocks 24..55 : A[m] = raw ||x_m||^2, xb (bf16)
// No inter-block dependencies: hv/C0 scaling deferred to k_pair.
__global__ __launch_bounds__(256) void k_prep(const float* __restrict__ cent,
                                              const float* __restrict__ x,
                                              const float* __restrict__ W1,
                                              const float* __restrict__ W2,
                                              const float* __restrict__ b2,
                                              float* __restrict__ part,
                                              float* __restrict__ A,
                                              float* __restrict__ B,
                                              unsigned short* __restrict__ xb,
                                              unsigned short* __restrict__ locb) {
    int b = blockIdx.x, t = threadIdx.x;

    if (b < 8) {
        const float4* c4 = (const float4*)cent;
        float s = 0.0f, q = 0.0f;
        #pragma unroll
        for (int i = 0; i < 16; i++) {
            float4 a = c4[b * 4096 + i * 256 + t];
            s += a.x + a.y + a.z + a.w;
            q += a.x * a.x + a.y * a.y + a.z * a.z + a.w * a.w;
        }
        #pragma unroll
        for (int off = 32; off > 0; off >>= 1) {
            s += __shfl_down(s, off);
            q += __shfl_down(q, off);
        }
        __shared__ float red[8];
        int lane = t & 63, wid = t >> 6;
        if (lane == 0) { red[wid] = s; red[4 + wid] = q; }
        __syncthreads();
        if (t == 0) {
            part[2 * b]     = red[0] + red[1] + red[2] + red[3];
            part[2 * b + 1] = red[4] + red[5] + red[6] + red[7];
        }
    } else if (b < 24) {
        __shared__ float w1s[HID * DIMS];
        __shared__ float w2s[DIMS * HID];
        __shared__ __align__(16) float ms[DIMS * DIMS];
        __shared__ float b2s[DIMS];
        for (int i = t; i < HID * DIMS; i += 256) { w1s[i] = W1[i]; w2s[i] = W2[i]; }
        if (t < DIMS) b2s[t] = b2[t];
        __syncthreads();
        #pragma unroll
        for (int o = 0; o < 4; o++) {
            int id = o * 256 + t;
            int r = id >> 5, cc = id & 31;
            float a = 0.0f;
            for (int j = 0; j < HID; j++) a += w2s[r * HID + j] * w1s[j * DIMS + cc];
            ms[id] = a;
        }
        __syncthreads();

        int n = (b - 8) * 256 + t;  // 0..4095
        float c[DIMS];
        const float4* cr = (const float4*)(cent + (size_t)n * DIMS);
        #pragma unroll
        for (int i = 0; i < 8; i++) {
            float4 v = cr[i];
            c[4 * i] = v.x; c[4 * i + 1] = v.y; c[4 * i + 2] = v.z; c[4 * i + 3] = v.w;
        }
        float lr[DIMS];
        float lsq = 0.0f;
        #pragma unroll
        for (int d = 0; d < DIMS; d++) {
            const float4* mr = (const float4*)&ms[d * DIMS];
            float a0 = 0.f, a1 = 0.f, a2 = 0.f, a3 = 0.f;
            #pragma unroll
            for (int kk = 0; kk < 8; kk++) {
                float4 m = mr[kk];
                a0 += c[4 * kk] * m.x;
                a1 += c[4 * kk + 1] * m.y;
                a2 += c[4 * kk + 2] * m.z;
                a3 += c[4 * kk + 3] * m.w;
            }
            float v = tanh_fast((a0 + a1) + (a2 + a3) + b2s[d]) * c[d];
            lr[d] = v;
            lsq += v * v;
        }
        unsigned int w[16];
        #pragma unroll
        for (int d = 0; d < 16; d++)
            w[d] = (unsigned int)f2bf(lr[2 * d]) | ((unsigned int)f2bf(lr[2 * d + 1]) << 16);
        uint4* lo = (uint4*)(locb + (size_t)n * DIMS);
        lo[0] = make_uint4(w[0], w[1], w[2], w[3]);
        lo[1] = make_uint4(w[4], w[5], w[6], w[7]);
        lo[2] = make_uint4(w[8], w[9], w[10], w[11]);
        lo[3] = make_uint4(w[12], w[13], w[14], w[15]);
        B[n] = lsq;  // raw; scaled by hv in k_pair
    } else {
        int m = (b - 24) * 256 + t;  // 0..8191
        const float4* xr = (const float4*)(x + (size_t)m * DIMS);
        float xsq = 0.0f;
        unsigned int w[16];
        #pragma unroll
        for (int i = 0; i < 8; i++) {
            float4 v = xr[i];
            xsq += v.x * v.x + v.y * v.y + v.z * v.z + v.w * v.w;
            w[2 * i]     = (unsigned int)f2bf(v.x) | ((unsigned int)f2bf(v.y) << 16);
            w[2 * i + 1] = (unsigned int)f2bf(v.z) | ((unsigned int)f2bf(v.w) << 16);
        }
        uint4* xo = (uint4*)(xb + (size_t)m * DIMS);
        xo[0] = make_uint4(w[0], w[1], w[2], w[3]);
        xo[1] = make_uint4(w[4], w[5], w[6], w[7]);
        xo[2] = make_uint4(w[8], w[9], w[10], w[11]);
        xo[3] = make_uint4(w[12], w[13], w[14], w[15]);
        A[m] = xsq;  // raw; hv/C0 applied in k_pair
    }
}

// ---------------- Kernel 2: pairwise exp tile via MFMA, no LDS -------------------
// out[m,n] = exp2(s*dot(loc_n,x_m) + hv*(xsq_m + lsq_n) + C0)
// Operand-swapped MFMA: acc = mfma(loc_frag, x_frag) puts n on the D row axis, so
// the 4 accumulator regs are 4 CONSECUTIVE n for fixed m -> one f32x4 store per
// fragment (16 stores/thread, temporal; proven best of the {NT,temporal} x
// {scattered,contiguous} matrix at 159.7 us).
// XCD-bijective tile swizzle: each XCD writes a contiguous 16 MB output slab.
__global__ __launch_bounds__(256) void k_pair(const unsigned short* __restrict__ xb,
                                              const unsigned short* __restrict__ locb,
                                              const float* __restrict__ A,
                                              const float* __restrict__ B,
                                              const float* __restrict__ part,
                                              float* __restrict__ out) {
    float iv, var;
    load_var(part, iv, var);
    const float s  = L2E * iv;
    const float hv = -0.5f * L2E * iv;
    const float C0 = -16.0f * log2f(2.0f * (float)M_PI * var);

    int t = threadIdx.x;
    int lane = t & 63, wid = t >> 6;
    int bid = blockIdx.x;
    int tile = ((bid & 7) << 8) | (bid >> 3);  // 2048 = 8*256: bijective
    int mt = tile >> 5, ntl = tile & 31;
    int m0 = mt * 128 + (wid >> 1) * 64;
    int n0 = ntl * 128 + (wid & 1) * 64;
    int r = lane & 15, g = lane >> 4;

    // Fragments: A-operand = loc (n on D rows), B-operand = x (m on D cols).
    // Both load as contiguous, fully-coalesced 1 KB segments (L2-resident).
    bf16x8 lf[4], xf[4];
    #pragma unroll
    for (int j = 0; j < 4; j++)
        lf[j] = *(const bf16x8*)(locb + (size_t)(n0 + 16 * j + r) * DIMS + 8 * g);
    #pragma unroll
    for (int i = 0; i < 4; i++)
        xf[i] = *(const bf16x8*)(xb + (size_t)(m0 + 16 * i + r) * DIMS + 8 * g);

    f32x4 zero = {0.0f, 0.0f, 0.0f, 0.0f};
    f32x4 acc[4][4];
    #pragma unroll
    for (int j = 0; j < 4; j++)
        #pragma unroll
        for (int i = 0; i < 4; i++)
            acc[j][i] = __builtin_amdgcn_mfma_f32_16x16x32_bf16(lf[j], xf[i], zero, 0, 0, 0);

    // D layout: col = lane&15 -> m = m0+16i+r;  row = 4*(lane>>4)+reg -> n = n0+16j+4g+q
    float em[4];
    #pragma unroll
    for (int i = 0; i < 4; i++)
        em[i] = fmaf(hv, A[m0 + 16 * i + r], C0);
    f32x4 en[4];
    #pragma unroll
    for (int j = 0; j < 4; j++) {
        float4 bv = *(const float4*)&B[n0 + 16 * j + 4 * g];
        en[j].x = hv * bv.x; en[j].y = hv * bv.y; en[j].z = hv * bv.z; en[j].w = hv * bv.w;
    }

    #pragma unroll
    for (int i = 0; i < 4; i++) {
        float* orow = out + (size_t)(m0 + 16 * i + r) * NROWS;
        float e = em[i];
        #pragma unroll
        for (int j = 0; j < 4; j++) {
            f32x4 v;
            v.x = __builtin_amdgcn_exp2f(fmaf(s, acc[j][i][0], e + en[j].x));
            v.y = __builtin_amdgcn_exp2f(fmaf(s, acc[j][i][1], e + en[j].y));
            v.z = __builtin_amdgcn_exp2f(fmaf(s, acc[j][i][2], e + en[j].z));
            v.w = __builtin_amdgcn_exp2f(fmaf(s, acc[j][i][3], e + en[j].w));
            *(f32x4*)(orow + n0 + 16 * j + 4 * g) = v;
        }
    }
}

extern "C" void kernel_launch(void* const* d_in, const int* in_sizes, int n_in,
                              void* d_out, int out_size, void* d_ws, size_t ws_size,
                              hipStream_t stream) {
    const float* cent = (const float*)d_in[0];
    const float* x    = (const float*)d_in[1];
    const float* W1   = (const float*)d_in[2];
    const float* W2   = (const float*)d_in[3];
    const float* b2   = (const float*)d_in[4];
    float* out = (float*)d_out;

    float* ws   = (float*)d_ws;
    float* part = ws;                      // 16 floats
    float* A    = ws + 64;                 // 8192 floats (raw xsq)
    float* B    = A + MROWS;               // 4096 floats (raw lsq)
    unsigned short* xb   = (unsigned short*)(B + NROWS);      // 8192*32 bf16 (512 KB)
    unsigned short* locb = xb + (size_t)MROWS * DIMS;         // 4096*32 bf16 (256 KB)

    k_prep<<<56, 256, 0, stream>>>(cent, x, W1, W2, b2, part, A, B, xb, locb);
    k_pair<<<NROWS / 128 * (MROWS / 128), 256, 0, stream>>>(xb, locb, A, B, part, out);
}